// Round 14
// baseline (71.351 us; speedup 1.0000x reference)
//
#include <hip/hip_runtime.h>
#include <math.h>

#define N_ATOMS 4096
#define SPECIES 100
#define FEA 64
#define M_NBR 12

typedef unsigned short u16;
typedef __attribute__((ext_vector_type(8))) _Float16 f16x8;
typedef __attribute__((ext_vector_type(4))) float f32x4;

constexpr float LN_EPS = 1e-5f;
constexpr float GAUSS_COEFF = -31.0078125f; // -0.5/(8/63)^2
constexpr float D2_INF = 3.4e38f;

__device__ __forceinline__ float sigmoidf_(float x){
    return __fdividef(1.0f, 1.0f + __expf(-x));
}
__device__ __forceinline__ float softplusf_(float x){
    return fmaxf(x, 0.0f) + __logf(1.0f + __expf(-fabsf(x)));
}
__device__ __forceinline__ u16 f16bits(_Float16 h){ return *(u16*)&h; }

// ---------------- setup: wpk pack + fracs transpose + embedding ----------------
// wpk: 6 mats (S1,N1,G1,S2,N2,G2) of 16KB fp16; within a mat:
// dest[((ch*8+nt)*64+lane)*8 + i] = W[k=ch*32+(lane>>4)*8+i][n=nt*16+(lane&15)]
__global__ __launch_bounds__(256) void k_setup(const float* __restrict__ fracs,
        const float* __restrict__ w1, const float* __restrict__ w2,
        const float* __restrict__ logits, const float* __restrict__ emb_w,
        const float* __restrict__ emb_b,
        float* __restrict__ fx, float* __restrict__ fy, float* __restrict__ fz,
        u16* __restrict__ wpk, float* __restrict__ atom0, u16* __restrict__ a0f){
    __shared__ float sE[4][SPECIES];
    int b = blockIdx.x, t = threadIdx.x;
    if (b < 192){
        int gid = b * 256 + t;
        int layer = gid / 24576;
        int e = gid % 24576;
        int k = e >> 7, n = e & 127;
        float x = (layer ? w2 : w1)[e];
        int mat = layer * 3 + (k >> 6);
        int kk = k & 63;
        int ch = kk >> 5, lg2 = (kk >> 3) & 3, i = kk & 7;
        int nt = n >> 4, lr2 = n & 15;
        wpk[mat * 8192 + ((ch * 8 + nt) * 64 + (lg2 * 16 + lr2)) * 8 + i] = f16bits((_Float16)x);
    } else if (b < 208){
        int j = (b - 192) * 256 + t;
        fx[j] = fracs[j*3+0];
        fy[j] = fracs[j*3+1];
        fz[j] = fracs[j*3+2];
    } else {
        int grp = t >> 6, f = t & 63;
        int a = (b - 208) * 4 + grp;
        const float* lg = logits + (long)a * SPECIES;
        float l0 = lg[f];
        float l1 = (f + 64 < SPECIES) ? lg[f + 64] : -1e30f;
        float mx = fmaxf(l0, l1);
        #pragma unroll
        for (int off = 32; off; off >>= 1) mx = fmaxf(mx, __shfl_xor(mx, off));
        float e0 = __expf(l0 - mx);
        float e1 = (f + 64 < SPECIES) ? __expf(l1 - mx) : 0.0f;
        sE[grp][f] = e0;
        if (f + 64 < SPECIES) sE[grp][64 + f] = e1;
        float sm = e0 + e1;
        #pragma unroll
        for (int off = 32; off; off >>= 1) sm += __shfl_xor(sm, off);
        __syncthreads();
        float acc = 0.0f;
        for (int s = 0; s < SPECIES; ++s) acc += sE[grp][s] * emb_w[s * FEA + f];
        float v = acc / sm + emb_b[f];
        atom0[(long)a * FEA + f] = v;
        a0f[a * FEA + f] = f16bits((_Float16)v);
    }
}

// ---------------- top-12: histogram threshold + compaction + parallel rank select ----------------
__global__ __launch_bounds__(256) void k_topk(const float* __restrict__ fx,
        const float* __restrict__ fy, const float* __restrict__ fz,
        const float* __restrict__ lat, int* __restrict__ nbr_idx,
        float* __restrict__ nbr_dist){
    __shared__ int   hist[256];
    __shared__ int   cnt;
    __shared__ float sThr;
    __shared__ float candD[256];
    __shared__ int   candI[256];
    int i = blockIdx.x, tid = threadIdx.x;
    hist[tid] = 0;
    if (tid == 0) cnt = 0;
    __syncthreads();
    float l00=lat[0],l01=lat[1],l02=lat[2];
    float l10=lat[3],l11=lat[4],l12=lat[5];
    float l20=lat[6],l21=lat[7],l22=lat[8];
    float xi = fx[i], yi = fy[i], zi = fz[i];
    float d2r[16];
    #pragma unroll
    for (int k = 0; k < 16; ++k){
        int j = tid + k * 256;
        float dx = xi - fx[j];
        float dy = yi - fy[j];
        float dz = zi - fz[j];
        dx -= rintf(dx); dy -= rintf(dy); dz -= rintf(dz);
        float cx = dx*l00 + dy*l10 + dz*l20;
        float cy = dx*l01 + dy*l11 + dz*l21;
        float cz = dx*l02 + dy*l12 + dz*l22;
        float d2 = cx*cx + cy*cy + cz*cz;
        if (j == i) d2 = D2_INF;
        d2r[k] = d2;
        if (d2 < 4.0f) atomicAdd(&hist[(int)(d2 * 64.0f)], 1);
    }
    __syncthreads();
    if (tid < 64){
        int s0 = hist[4*tid] + hist[4*tid+1] + hist[4*tid+2] + hist[4*tid+3];
        int sc = s0;
        #pragma unroll
        for (int off = 1; off < 64; off <<= 1){
            int o = __shfl_up(sc, off);
            if (tid >= off) sc += o;
        }
        unsigned long long mball = __ballot(sc >= M_NBR);
        if (mball == 0ULL){
            if (tid == 0) sThr = 1e30f;
        } else {
            int gbin = __ffsll(mball) - 1;
            if (tid == gbin){
                int c = sc - s0;
                float th = 4.0f;
                #pragma unroll
                for (int b = 0; b < 4; ++b){
                    c += hist[4*gbin + b];
                    if (c >= M_NBR){ th = (float)(4*gbin + b + 1) * (1.0f/64.0f); break; }
                }
                sThr = th;
            }
        }
    }
    __syncthreads();
    float thr = sThr;
    #pragma unroll
    for (int k = 0; k < 16; ++k){
        if (d2r[k] < thr){
            int p = atomicAdd(&cnt, 1);
            if (p < 256){ candD[p] = d2r[k]; candI[p] = tid + k * 256; }
        }
    }
    __syncthreads();
    int n = cnt < 256 ? cnt : 256;
    for (int c = tid; c < n; c += 256){
        float dv = candD[c]; int iv = candI[c];
        int rank = 0;
        for (int s = 0; s < n; ++s){
            float ds_ = candD[s]; int is_ = candI[s];
            rank += (ds_ < dv || (ds_ == dv && is_ < iv)) ? 1 : 0;
        }
        if (rank < M_NBR){
            nbr_idx[i * M_NBR + rank]  = iv;
            nbr_dist[i * M_NBR + rank] = sqrtf(dv);
        }
    }
}

// ---------------- precompute S1 = a0f @ Ws1 + b1 ----------------
__global__ __launch_bounds__(64) void k_precomp(const u16* __restrict__ a0f,
        const u16* __restrict__ wpk, const float* __restrict__ b1,
        float* __restrict__ S1){
    const int l = threadIdx.x;
    const int lg = l >> 4, lr = l & 15;
    const int blk = blockIdx.x;
    f16x8 af[2];
    #pragma unroll
    for (int c = 0; c < 2; ++c)
        af[c] = *(const f16x8*)(a0f + (blk * 16 + lr) * 64 + c * 32 + lg * 8);
    f32x4 acc[8];
    #pragma unroll
    for (int nt = 0; nt < 8; ++nt) acc[nt] = 0.0f;
    #pragma unroll
    for (int c = 0; c < 2; ++c)
        #pragma unroll
        for (int nt = 0; nt < 8; ++nt){
            const f16x8 b = *(const f16x8*)(wpk + ((c * 8 + nt) * 64 + l) * 8);
            acc[nt] = __builtin_amdgcn_mfma_f32_16x16x32_f16(af[c], b, acc[nt], 0, 0, 0);
        }
    #pragma unroll
    for (int nt = 0; nt < 8; ++nt)
        #pragma unroll
        for (int rr = 0; rr < 4; ++rr)
            S1[(blk * 16 + lg * 4 + rr) * 128 + nt * 16 + lr] = acc[nt][rr] + b1[nt * 16 + lr];
}

// ---------------- edge-feature build (im2col): X[group][c=4][lane][8] fp16 ----------------
// X row r = [a0f[nid[r]] (64) | gauss(dist[r]) (64)], stored pre-swizzled so the GEMM's
// A-fragment load is a wave-contiguous 1KB read. group = r/16; within a group, lane
// (lg,lr) chunk c holds X[group*16 + lr][c*32 + lg*8 .. +8].
__global__ __launch_bounds__(256) void k_edges(const u16* __restrict__ a0f,
        const int* __restrict__ nbr_idx, const float* __restrict__ nbr_dist,
        u16* __restrict__ X){
    const int blk = blockIdx.x, t = threadIdx.x;   // blk == group
    const int c = (t >> 6) & 3;
    const int lane = t & 63;
    const int sub = lane >> 4;                     // lg
    const int row = blk * 16 + (lane & 15);        // global edge row
    f16x8 v;
    if (c < 2){
        v = *(const f16x8*)(a0f + nbr_idx[row] * 64 + c * 32 + sub * 8);
    } else {
        float d = nbr_dist[row];
        #pragma unroll
        for (int i = 0; i < 8; ++i){
            int k = (c - 2) * 32 + sub * 8 + i;
            float dd = d - (float)k * (8.0f / 63.0f);
            v[i] = (_Float16)__expf(GAUSS_COEFF * dd * dd);
        }
    }
    *(f16x8*)(X + ((long)blk * 256 + t) * 8) = v;
}

// ---------------- both-layer edge GEMM + LN + act + reduce ----------------
// Block = 192 thr (3 waves x 16 rows) = 48 rows = 4 atoms; grid 1024.
// A from prebuilt X (wave-contiguous), B from global wpk (64KB total, L1-hot),
// S1 precomputed+staged; S2 per-wave in-block mini-GEMM. 3 barriers.
__global__ __launch_bounds__(192) void k_gemm(
        const float* __restrict__ atom0F, const u16* __restrict__ X,
        const u16* __restrict__ wpk, const float* __restrict__ S1g,
        const float* __restrict__ b2,
        const float* __restrict__ g1, const float* __restrict__ be1,
        const float* __restrict__ g2, const float* __restrict__ be2,
        float* __restrict__ outF)
{
    __shared__ float sS1[4][132];
    __shared__ float sS2w[3][4][132];
    __shared__ float prod[48][65];
    __shared__ float sSF[4][64];
    __shared__ u16   sSH[4][64];

    const int t = threadIdx.x;
    const int w = t >> 6, l = t & 63;
    const int lg = l >> 4, lr = l & 15;
    const int blk = blockIdx.x;

    // stage S1 rows (4 x 128 f32, bias folded)
    if (t < 128){
        int a_ = t >> 5, c4 = (t & 31) << 2;
        *(float4*)(&sS1[a_][c4]) = *(const float4*)(S1g + (long)(blk * 4 + a_) * 128 + c4);
    }

    // A-fragments: 4 wave-contiguous 1KB loads
    f16x8 af[4];
    #pragma unroll
    for (int c = 0; c < 4; ++c)
        af[c] = *(const f16x8*)(X + (((long)(blk * 3 + w) * 4 + c) * 64 + l) * 8);

    // residual prefetch
    float res0 = atom0F[(long)blk * 256 + t];
    float res1 = (t < 64) ? atom0F[(long)blk * 256 + 192 + t] : 0.0f;

    float g1v[8], be1v[8], g2v[8], be2v[8], b2v[8];
    #pragma unroll
    for (int nt = 0; nt < 8; ++nt){
        int c = nt * 16 + lr;
        g1v[nt] = g1[c]; be1v[nt] = be1[c];
        g2v[nt] = g2[c]; be2v[nt] = be2[c];
        b2v[nt] = b2[c];
    }

    int aloc[4];
    #pragma unroll
    for (int rr = 0; rr < 4; ++rr)
        aloc[rr] = (w * 16 + lg * 4 + rr) / 12;

    // ---- layer-1 edge MFMA: B c<2 from N1 (mat1), c>=2 from G1 (mat2) ----
    f32x4 acc[8];
    #pragma unroll
    for (int nt = 0; nt < 8; ++nt) acc[nt] = 0.0f;
    #pragma unroll
    for (int c = 0; c < 4; ++c)
        #pragma unroll
        for (int nt = 0; nt < 8; ++nt){
            const u16* bm = (c < 2)
                ? wpk + 1 * 8192 + ((c * 8 + nt) * 64 + l) * 8
                : wpk + 2 * 8192 + (((c - 2) * 8 + nt) * 64 + l) * 8;
            acc[nt] = __builtin_amdgcn_mfma_f32_16x16x32_f16(af[c], *(const f16x8*)bm, acc[nt], 0, 0, 0);
        }
    __syncthreads();   // B1: sS1 staged

    // z1 = acc + S1; LN1; products
    {
        float s[4] = {0,0,0,0}, q[4] = {0,0,0,0};
        #pragma unroll
        for (int nt = 0; nt < 8; ++nt)
            #pragma unroll
            for (int rr = 0; rr < 4; ++rr){
                float v = acc[nt][rr] + sS1[aloc[rr]][nt * 16 + lr];
                acc[nt][rr] = v;
                s[rr] += v; q[rr] += v * v;
            }
        #pragma unroll
        for (int rr = 0; rr < 4; ++rr){
            #pragma unroll
            for (int m = 1; m < 16; m <<= 1){
                s[rr] += __shfl_xor(s[rr], m);
                q[rr] += __shfl_xor(q[rr], m);
            }
        }
        #pragma unroll
        for (int rr = 0; rr < 4; ++rr){
            float mean = s[rr] * (1.0f / 128.0f);
            float var  = q[rr] * (1.0f / 128.0f) - mean * mean;
            float inv  = rsqrtf(var + LN_EPS);
            #pragma unroll
            for (int nt = 0; nt < 4; ++nt){
                float zf = (acc[nt][rr]     - mean) * inv * g1v[nt]     + be1v[nt];
                float zc = (acc[nt + 4][rr] - mean) * inv * g1v[nt + 4] + be1v[nt + 4];
                prod[w * 16 + lg * 4 + rr][nt * 16 + lr] = sigmoidf_(zf) * softplusf_(zc);
            }
        }
    }
    __syncthreads();   // B2: prod1 complete

    // epilogue 1 (256 items over 192 threads)
    {
        int a_ = t >> 6, c = t & 63;
        float sm = 0.0f;
        #pragma unroll
        for (int m = 0; m < 12; ++m) sm += prod[a_ * 12 + m][c];
        float o = softplusf_(res0 + sm);
        sSF[a_][c] = o; sSH[a_][c] = f16bits((_Float16)o);
        if (t < 64){
            float sm2 = 0.0f;
            #pragma unroll
            for (int m = 0; m < 12; ++m) sm2 += prod[36 + m][c];
            float o2 = softplusf_(res1 + sm2);
            sSF[3][c] = o2; sSH[3][c] = f16bits((_Float16)o2);
        }
    }
    __syncthreads();   // B3: sSF/sSH ready

    // S2 mini-GEMM, per wave (intra-wave LDS, no barrier)
    {
        f16x8 af2[2];
        #pragma unroll
        for (int c = 0; c < 2; ++c)
            af2[c] = (lr < 4) ? *(const f16x8*)(&sSH[lr][c * 32 + lg * 8]) : (f16x8)0;
        f32x4 a2[8];
        #pragma unroll
        for (int nt = 0; nt < 8; ++nt) a2[nt] = 0.0f;
        #pragma unroll
        for (int c = 0; c < 2; ++c)
            #pragma unroll
            for (int nt = 0; nt < 8; ++nt){
                const f16x8 b = *(const f16x8*)(wpk + 3 * 8192 + ((c * 8 + nt) * 64 + l) * 8);
                a2[nt] = __builtin_amdgcn_mfma_f32_16x16x32_f16(af2[c], b, a2[nt], 0, 0, 0);
            }
        if (lg == 0){
            #pragma unroll
            for (int nt = 0; nt < 8; ++nt)
                #pragma unroll
                for (int rr = 0; rr < 4; ++rr)
                    sS2w[w][rr][nt * 16 + lr] = a2[nt][rr] + b2v[nt];
        }
    }

    // ---- layer-2 edge MFMA (af reused): B from N2 (mat4) / G2 (mat5) ----
    f32x4 acc2[8];
    #pragma unroll
    for (int nt = 0; nt < 8; ++nt) acc2[nt] = 0.0f;
    #pragma unroll
    for (int c = 0; c < 4; ++c)
        #pragma unroll
        for (int nt = 0; nt < 8; ++nt){
            const u16* bm = (c < 2)
                ? wpk + 4 * 8192 + ((c * 8 + nt) * 64 + l) * 8
                : wpk + 5 * 8192 + (((c - 2) * 8 + nt) * 64 + l) * 8;
            acc2[nt] = __builtin_amdgcn_mfma_f32_16x16x32_f16(af[c], *(const f16x8*)bm, acc2[nt], 0, 0, 0);
        }

    // z2 = acc2 + S2 (wave-local); LN2; products
    {
        float s[4] = {0,0,0,0}, q[4] = {0,0,0,0};
        #pragma unroll
        for (int nt = 0; nt < 8; ++nt)
            #pragma unroll
            for (int rr = 0; rr < 4; ++rr){
                float v = acc2[nt][rr] + sS2w[w][aloc[rr]][nt * 16 + lr];
                acc2[nt][rr] = v;
                s[rr] += v; q[rr] += v * v;
            }
        #pragma unroll
        for (int rr = 0; rr < 4; ++rr){
            #pragma unroll
            for (int m = 1; m < 16; m <<= 1){
                s[rr] += __shfl_xor(s[rr], m);
                q[rr] += __shfl_xor(q[rr], m);
            }
        }
        #pragma unroll
        for (int rr = 0; rr < 4; ++rr){
            float mean = s[rr] * (1.0f / 128.0f);
            float var  = q[rr] * (1.0f / 128.0f) - mean * mean;
            float inv  = rsqrtf(var + LN_EPS);
            #pragma unroll
            for (int nt = 0; nt < 4; ++nt){
                float zf = (acc2[nt][rr]     - mean) * inv * g2v[nt]     + be2v[nt];
                float zc = (acc2[nt + 4][rr] - mean) * inv * g2v[nt + 4] + be2v[nt + 4];
                prod[w * 16 + lg * 4 + rr][nt * 16 + lr] = sigmoidf_(zf) * softplusf_(zc);
            }
        }
    }
    __syncthreads();   // B4: prod2 complete

    // epilogue 2 -> outF
    {
        int a_ = t >> 6, c = t & 63;
        float sm = 0.0f;
        #pragma unroll
        for (int m = 0; m < 12; ++m) sm += prod[a_ * 12 + m][c];
        outF[(long)blk * 256 + t] = softplusf_(sSF[a_][c] + sm);
        if (t < 64){
            float sm2 = 0.0f;
            #pragma unroll
            for (int m = 0; m < 12; ++m) sm2 += prod[36 + m][c];
            outF[(long)blk * 256 + 192 + t] = softplusf_(sSF[3][c] + sm2);
        }
    }
}

// ---------------- pooling: deterministic two-stage tree ----------------
__global__ __launch_bounds__(256) void k_partial(const float* __restrict__ atom,
        const float* __restrict__ occ, float* __restrict__ partials){
    int b = blockIdx.x, tid = threadIdx.x;
    int f = tid & 63, sub = tid >> 6;
    __shared__ float sAcc[256];
    float acc = 0.0f;
    for (int it = 0; it < 16; ++it){
        int a = b * 64 + sub + it * 4;
        float p = sigmoidf_(occ[a]);
        acc += atom[(long)a * FEA + f] * p;
    }
    sAcc[tid] = acc;
    __syncthreads();
    if (tid < 64){
        float s = sAcc[f] + sAcc[64 + f] + sAcc[128 + f] + sAcc[192 + f];
        partials[b * 65 + f] = s;
        float po = sigmoidf_(occ[b * 64 + f]);
        #pragma unroll
        for (int off = 32; off; off >>= 1) po += __shfl_down(po, off);
        if (f == 0) partials[b * 65 + 64] = po;
    }
}

__global__ __launch_bounds__(64) void k_final(const float* __restrict__ partials,
        const float* __restrict__ fc_w, const float* __restrict__ fc_b,
        float* __restrict__ out){
    int f = threadIdx.x;
    float num = 0.0f;
    for (int p = 0; p < 64; ++p) num += partials[p * 65 + f];
    float occs = partials[f * 65 + 64];
    #pragma unroll
    for (int off = 32; off; off >>= 1) occs += __shfl_down(occs, off);
    occs = __shfl(occs, 0);
    float gf = num / (occs + 1e-6f);
    float v = gf * fc_w[f];
    #pragma unroll
    for (int off = 32; off; off >>= 1) v += __shfl_down(v, off);
    if (f == 0) out[0] = v + fc_b[0];
}

extern "C" void kernel_launch(void* const* d_in, const int* in_sizes, int n_in,
                              void* d_out, int out_size, void* d_ws, size_t ws_size,
                              hipStream_t stream) {
    const float* lat    = (const float*)d_in[0];
    const float* fracs  = (const float*)d_in[1];
    const float* slog   = (const float*)d_in[2];
    const float* occ    = (const float*)d_in[3];
    const float* emb_w  = (const float*)d_in[4];
    const float* emb_b  = (const float*)d_in[5];
    const float* w1     = (const float*)d_in[6];
    const float* b1     = (const float*)d_in[7];
    const float* g1     = (const float*)d_in[8];
    const float* be1    = (const float*)d_in[9];
    const float* w2     = (const float*)d_in[10];
    const float* b2     = (const float*)d_in[11];
    const float* g2     = (const float*)d_in[12];
    const float* be2    = (const float*)d_in[13];
    const float* fc_w   = (const float*)d_in[14];
    const float* fc_b   = (const float*)d_in[15];
    float* out = (float*)d_out;

    char* ws = (char*)d_ws;
    auto alloc = [&](size_t bytes) -> void* {
        void* p = (void*)ws;
        ws += (bytes + 255) & ~(size_t)255;
        return p;
    };
    int*   nbr_idx  = (int*)  alloc((size_t)N_ATOMS * M_NBR * 4);
    float* nbr_dist = (float*)alloc((size_t)N_ATOMS * M_NBR * 4);
    float* atom0    = (float*)alloc((size_t)N_ATOMS * FEA * 4);
    float* atom1    = (float*)alloc((size_t)N_ATOMS * FEA * 4);
    u16*   a0f      = (u16*)  alloc((size_t)N_ATOMS * FEA * 2);
    u16*   wpk      = (u16*)  alloc((size_t)6 * 8192 * 2);
    float* S1       = (float*)alloc((size_t)N_ATOMS * 128 * 4);
    u16*   X        = (u16*)  alloc((size_t)N_ATOMS * M_NBR * 128 * 2);
    float* fxa      = (float*)alloc((size_t)N_ATOMS * 4);
    float* fya      = (float*)alloc((size_t)N_ATOMS * 4);
    float* fza      = (float*)alloc((size_t)N_ATOMS * 4);
    float* partials = (float*)alloc((size_t)64 * 65 * 4);

    k_setup  <<<208 + N_ATOMS / 4, 256, 0, stream>>>(fracs, w1, w2, slog, emb_w, emb_b,
                fxa, fya, fza, wpk, atom0, a0f);
    k_topk   <<<N_ATOMS, 256, 0, stream>>>(fxa, fya, fza, lat, nbr_idx, nbr_dist);
    k_precomp<<<N_ATOMS / 16, 64, 0, stream>>>(a0f, wpk, b1, S1);
    k_edges  <<<N_ATOMS * M_NBR / 16, 256, 0, stream>>>(a0f, nbr_idx, nbr_dist, X);
    k_gemm   <<<N_ATOMS / 4, 192, 0, stream>>>(atom0, X, wpk, S1, b2,
                g1, be1, g2, be2, atom1);
    k_partial<<<64, 256, 0, stream>>>(atom1, occ, partials);
    k_final  <<<1, 64, 0, stream>>>(partials, fc_w, fc_b, out);
}

// Round 15
// 60.643 us; speedup vs baseline: 1.1766x; 1.1766x over previous
//
#include <hip/hip_runtime.h>
#include <math.h>

#define N_ATOMS 4096
#define SPECIES 100
#define FEA 64
#define M_NBR 12

typedef unsigned short u16;
typedef __attribute__((ext_vector_type(8))) _Float16 f16x8;
typedef __attribute__((ext_vector_type(4))) float f32x4;

constexpr float LN_EPS = 1e-5f;
constexpr float GAUSS_COEFF = -31.0078125f; // -0.5/(8/63)^2
constexpr float D2_INF = 3.4e38f;

__device__ __forceinline__ float sigmoidf_(float x){
    return __fdividef(1.0f, 1.0f + __expf(-x));
}
__device__ __forceinline__ float softplusf_(float x){
    return fmaxf(x, 0.0f) + __logf(1.0f + __expf(-fabsf(x)));
}
__device__ __forceinline__ u16 f16bits(_Float16 h){ return *(u16*)&h; }

// ---------------- setup: wpk pack + fracs transpose + embedding ----------------
// wpk: 6 mats (S1,N1,G1,S2,N2,G2) of 16KB fp16; within a mat:
// dest[((ch*8+nt)*64+lane)*8 + i] = W[k=ch*32+(lane>>4)*8+i][n=nt*16+(lane&15)]
__global__ __launch_bounds__(256) void k_setup(const float* __restrict__ fracs,
        const float* __restrict__ w1, const float* __restrict__ w2,
        const float* __restrict__ logits, const float* __restrict__ emb_w,
        const float* __restrict__ emb_b,
        float* __restrict__ fx, float* __restrict__ fy, float* __restrict__ fz,
        u16* __restrict__ wpk, float* __restrict__ atom0, u16* __restrict__ a0f){
    __shared__ float sE[4][SPECIES];
    int b = blockIdx.x, t = threadIdx.x;
    if (b < 192){
        int gid = b * 256 + t;
        int layer = gid / 24576;
        int e = gid % 24576;
        int k = e >> 7, n = e & 127;
        float x = (layer ? w2 : w1)[e];
        int mat = layer * 3 + (k >> 6);
        int kk = k & 63;
        int ch = kk >> 5, lg2 = (kk >> 3) & 3, i = kk & 7;
        int nt = n >> 4, lr2 = n & 15;
        wpk[mat * 8192 + ((ch * 8 + nt) * 64 + (lg2 * 16 + lr2)) * 8 + i] = f16bits((_Float16)x);
    } else if (b < 208){
        int j = (b - 192) * 256 + t;
        fx[j] = fracs[j*3+0];
        fy[j] = fracs[j*3+1];
        fz[j] = fracs[j*3+2];
    } else {
        int grp = t >> 6, f = t & 63;
        int a = (b - 208) * 4 + grp;
        const float* lg = logits + (long)a * SPECIES;
        float l0 = lg[f];
        float l1 = (f + 64 < SPECIES) ? lg[f + 64] : -1e30f;
        float mx = fmaxf(l0, l1);
        #pragma unroll
        for (int off = 32; off; off >>= 1) mx = fmaxf(mx, __shfl_xor(mx, off));
        float e0 = __expf(l0 - mx);
        float e1 = (f + 64 < SPECIES) ? __expf(l1 - mx) : 0.0f;
        sE[grp][f] = e0;
        if (f + 64 < SPECIES) sE[grp][64 + f] = e1;
        float sm = e0 + e1;
        #pragma unroll
        for (int off = 32; off; off >>= 1) sm += __shfl_xor(sm, off);
        __syncthreads();
        float acc = 0.0f;
        for (int s = 0; s < SPECIES; ++s) acc += sE[grp][s] * emb_w[s * FEA + f];
        float v = acc / sm + emb_b[f];
        atom0[(long)a * FEA + f] = v;
        a0f[a * FEA + f] = f16bits((_Float16)v);
    }
}

// ---------------- top-12: histogram threshold + compaction + parallel rank select ----------------
__global__ __launch_bounds__(256) void k_topk(const float* __restrict__ fx,
        const float* __restrict__ fy, const float* __restrict__ fz,
        const float* __restrict__ lat, int* __restrict__ nbr_idx,
        float* __restrict__ nbr_dist){
    __shared__ int   hist[256];
    __shared__ int   cnt;
    __shared__ float sThr;
    __shared__ float candD[256];
    __shared__ int   candI[256];
    int i = blockIdx.x, tid = threadIdx.x;
    hist[tid] = 0;
    if (tid == 0) cnt = 0;
    __syncthreads();
    float l00=lat[0],l01=lat[1],l02=lat[2];
    float l10=lat[3],l11=lat[4],l12=lat[5];
    float l20=lat[6],l21=lat[7],l22=lat[8];
    float xi = fx[i], yi = fy[i], zi = fz[i];
    float d2r[16];
    #pragma unroll
    for (int k = 0; k < 16; ++k){
        int j = tid + k * 256;
        float dx = xi - fx[j];
        float dy = yi - fy[j];
        float dz = zi - fz[j];
        dx -= rintf(dx); dy -= rintf(dy); dz -= rintf(dz);
        float cx = dx*l00 + dy*l10 + dz*l20;
        float cy = dx*l01 + dy*l11 + dz*l21;
        float cz = dx*l02 + dy*l12 + dz*l22;
        float d2 = cx*cx + cy*cy + cz*cz;
        if (j == i) d2 = D2_INF;
        d2r[k] = d2;
        if (d2 < 4.0f) atomicAdd(&hist[(int)(d2 * 64.0f)], 1);
    }
    __syncthreads();
    if (tid < 64){
        int s0 = hist[4*tid] + hist[4*tid+1] + hist[4*tid+2] + hist[4*tid+3];
        int sc = s0;
        #pragma unroll
        for (int off = 1; off < 64; off <<= 1){
            int o = __shfl_up(sc, off);
            if (tid >= off) sc += o;
        }
        unsigned long long mball = __ballot(sc >= M_NBR);
        if (mball == 0ULL){
            if (tid == 0) sThr = 1e30f;
        } else {
            int gbin = __ffsll(mball) - 1;
            if (tid == gbin){
                int c = sc - s0;
                float th = 4.0f;
                #pragma unroll
                for (int b = 0; b < 4; ++b){
                    c += hist[4*gbin + b];
                    if (c >= M_NBR){ th = (float)(4*gbin + b + 1) * (1.0f/64.0f); break; }
                }
                sThr = th;
            }
        }
    }
    __syncthreads();
    float thr = sThr;
    #pragma unroll
    for (int k = 0; k < 16; ++k){
        if (d2r[k] < thr){
            int p = atomicAdd(&cnt, 1);
            if (p < 256){ candD[p] = d2r[k]; candI[p] = tid + k * 256; }
        }
    }
    __syncthreads();
    int n = cnt < 256 ? cnt : 256;
    for (int c = tid; c < n; c += 256){
        float dv = candD[c]; int iv = candI[c];
        int rank = 0;
        for (int s = 0; s < n; ++s){
            float ds_ = candD[s]; int is_ = candI[s];
            rank += (ds_ < dv || (ds_ == dv && is_ < iv)) ? 1 : 0;
        }
        if (rank < M_NBR){
            nbr_idx[i * M_NBR + rank]  = iv;
            nbr_dist[i * M_NBR + rank] = sqrtf(dv);
        }
    }
}

// ---------------- fused CGCNN layers 1+2, mt=2: 8 atoms/block, grid 512 ----------------
// Block = 192 thr (3 waves x 2 M-tiles x 16 rows = 96 rows = 8 atoms); 2 blocks/CU.
// Each B-fragment load feeds 2 MFMAs; per-wave S1/S2 mini-GEMMs serve 8 atoms.
// Per-CU B-traffic halves vs the 4-atom geometry. B read directly from global (L1/L2).
__global__ __launch_bounds__(192) void k_fused(
        const float* __restrict__ atom0F, const u16* __restrict__ a0f,
        const int* __restrict__ nbr_idx, const float* __restrict__ nbr_dist,
        const u16* __restrict__ wpk,
        const float* __restrict__ b1, const float* __restrict__ g1, const float* __restrict__ be1,
        const float* __restrict__ b2, const float* __restrict__ g2, const float* __restrict__ be2,
        float* __restrict__ outF)
{
    __shared__ float sSw[3][8][132];  // per-wave self-GEMM result (+bias); S1 then S2
    __shared__ float prod[96][65];    // 24.9KB
    __shared__ float sSF[8][64];      // layer-1 out f32 (residual)
    __shared__ u16   sSH[8][64];      // layer-1 out fp16

    const int t = threadIdx.x;
    const int w = t >> 6, l = t & 63;
    const int lg = l >> 4, lr = l & 15;
    const int blk = blockIdx.x;

    // ---- prologue: issue all independent loads ----
    int nid[2]; float dist[2];
    #pragma unroll
    for (int mt = 0; mt < 2; ++mt){
        int row = blk * 96 + w * 32 + mt * 16 + lr;
        nid[mt]  = nbr_idx[row];
        dist[mt] = nbr_dist[row];
    }
    f16x8 nfr[2][2];
    #pragma unroll
    for (int mt = 0; mt < 2; ++mt){
        nfr[mt][0] = *(const f16x8*)(a0f + nid[mt] * 64 + lg * 8);
        nfr[mt][1] = *(const f16x8*)(a0f + nid[mt] * 64 + 32 + lg * 8);
    }
    f16x8 saf[2];
    #pragma unroll
    for (int c = 0; c < 2; ++c)
        saf[c] = (lr < 8) ? *(const f16x8*)(a0f + (blk * 8 + lr) * 64 + c * 32 + lg * 8)
                          : (f16x8)0;
    float res[3];
    res[0] = atom0F[(long)blk * 512 + t];
    res[1] = atom0F[(long)blk * 512 + 192 + t];
    res[2] = (t < 128) ? atom0F[(long)blk * 512 + 384 + t] : 0.0f;

    float g1v[8], be1v[8], b1v[8];
    #pragma unroll
    for (int nt = 0; nt < 8; ++nt){
        int c = nt * 16 + lr;
        g1v[nt] = g1[c]; be1v[nt] = be1[c]; b1v[nt] = b1[c];
    }

    f16x8 ga[2][2];
    #pragma unroll
    for (int mt = 0; mt < 2; ++mt)
        #pragma unroll
        for (int c = 0; c < 2; ++c)
            #pragma unroll
            for (int i = 0; i < 8; ++i){
                int k = c * 32 + lg * 8 + i;
                float dd = dist[mt] - (float)k * (8.0f / 63.0f);
                ga[mt][c][i] = (_Float16)__expf(GAUSS_COEFF * dd * dd);
            }

    int aloc[2][4];
    #pragma unroll
    for (int mt = 0; mt < 2; ++mt)
        #pragma unroll
        for (int rr = 0; rr < 4; ++rr)
            aloc[mt][rr] = (w * 32 + mt * 16 + lg * 4 + rr) / 12;

    const u16* ws1 = wpk;
    const u16* wn1 = wpk + 1 * 8192;
    const u16* wg1 = wpk + 2 * 8192;
    const u16* ws2 = wpk + 3 * 8192;
    const u16* wn2 = wpk + 4 * 8192;
    const u16* wg2 = wpk + 5 * 8192;

    // ---- S1 mini-GEMM per wave (8 atoms; intra-wave LDS, no barrier) ----
    {
        f32x4 a1[8];
        #pragma unroll
        for (int nt = 0; nt < 8; ++nt) a1[nt] = 0.0f;
        #pragma unroll
        for (int c = 0; c < 2; ++c)
            #pragma unroll
            for (int nt = 0; nt < 8; ++nt){
                const f16x8 b = *(const f16x8*)(ws1 + ((c * 8 + nt) * 64 + l) * 8);
                a1[nt] = __builtin_amdgcn_mfma_f32_16x16x32_f16(saf[c], b, a1[nt], 0, 0, 0);
            }
        if (lg < 2){
            #pragma unroll
            for (int nt = 0; nt < 8; ++nt)
                #pragma unroll
                for (int rr = 0; rr < 4; ++rr)
                    sSw[w][lg * 4 + rr][nt * 16 + lr] = a1[nt][rr] + b1v[nt];
        }
    }

    // ---- layer-1 edge MFMA (each B load feeds both mt) ----
    f32x4 acc[2][8];
    #pragma unroll
    for (int mt = 0; mt < 2; ++mt)
        #pragma unroll
        for (int nt = 0; nt < 8; ++nt) acc[mt][nt] = 0.0f;
    #pragma unroll
    for (int c = 0; c < 2; ++c)
        #pragma unroll
        for (int nt = 0; nt < 8; ++nt){
            const f16x8 bn = *(const f16x8*)(wn1 + ((c * 8 + nt) * 64 + l) * 8);
            const f16x8 bg = *(const f16x8*)(wg1 + ((c * 8 + nt) * 64 + l) * 8);
            #pragma unroll
            for (int mt = 0; mt < 2; ++mt){
                acc[mt][nt] = __builtin_amdgcn_mfma_f32_16x16x32_f16(nfr[mt][c], bn, acc[mt][nt], 0, 0, 0);
                acc[mt][nt] = __builtin_amdgcn_mfma_f32_16x16x32_f16(ga[mt][c],  bg, acc[mt][nt], 0, 0, 0);
            }
        }

    // ---- z1 + LN1 -> prod ----
    #pragma unroll
    for (int mt = 0; mt < 2; ++mt){
        float s[4] = {0,0,0,0}, q[4] = {0,0,0,0};
        #pragma unroll
        for (int nt = 0; nt < 8; ++nt)
            #pragma unroll
            for (int rr = 0; rr < 4; ++rr){
                float v = acc[mt][nt][rr] + sSw[w][aloc[mt][rr]][nt * 16 + lr];
                acc[mt][nt][rr] = v;
                s[rr] += v; q[rr] += v * v;
            }
        #pragma unroll
        for (int rr = 0; rr < 4; ++rr){
            #pragma unroll
            for (int m = 1; m < 16; m <<= 1){
                s[rr] += __shfl_xor(s[rr], m);
                q[rr] += __shfl_xor(q[rr], m);
            }
        }
        #pragma unroll
        for (int rr = 0; rr < 4; ++rr){
            float mean = s[rr] * (1.0f / 128.0f);
            float var  = q[rr] * (1.0f / 128.0f) - mean * mean;
            float inv  = rsqrtf(var + LN_EPS);
            #pragma unroll
            for (int nt = 0; nt < 4; ++nt){
                float zf = (acc[mt][nt][rr]     - mean) * inv * g1v[nt]     + be1v[nt];
                float zc = (acc[mt][nt + 4][rr] - mean) * inv * g1v[nt + 4] + be1v[nt + 4];
                prod[w * 32 + mt * 16 + lg * 4 + rr][nt * 16 + lr] = sigmoidf_(zf) * softplusf_(zc);
            }
        }
    }
    __syncthreads();   // B1: prod1 complete

    // ---- epilogue 1 (512 items over 192 threads) -> sSF/sSH ----
    {
        int a_ = t >> 6, c = t & 63;
        float sm = 0.0f;
        #pragma unroll
        for (int m = 0; m < 12; ++m) sm += prod[a_ * 12 + m][c];
        float o = softplusf_(res[0] + sm);
        sSF[a_][c] = o; sSH[a_][c] = f16bits((_Float16)o);

        int i2 = t + 192; int a2_ = i2 >> 6, c2 = i2 & 63;
        float sm2 = 0.0f;
        #pragma unroll
        for (int m = 0; m < 12; ++m) sm2 += prod[a2_ * 12 + m][c2];
        float o2 = softplusf_(res[1] + sm2);
        sSF[a2_][c2] = o2; sSH[a2_][c2] = f16bits((_Float16)o2);

        if (t < 128){
            int i3 = t + 384; int a3_ = i3 >> 6, c3 = i3 & 63;
            float sm3 = 0.0f;
            #pragma unroll
            for (int m = 0; m < 12; ++m) sm3 += prod[a3_ * 12 + m][c3];
            float o3 = softplusf_(res[2] + sm3);
            sSF[a3_][c3] = o3; sSH[a3_][c3] = f16bits((_Float16)o3);
        }
    }
    __syncthreads();   // B2: sSF/sSH ready

    // preload gamma/beta layer 2 (after layer-1 regs die)
    float g2v[8], be2v[8], b2v[8];
    #pragma unroll
    for (int nt = 0; nt < 8; ++nt){
        int c = nt * 16 + lr;
        g2v[nt] = g2[c]; be2v[nt] = be2[c]; b2v[nt] = b2[c];
    }

    // ---- S2 mini-GEMM per wave (reuses sSw; intra-wave, no barrier) ----
    {
        f16x8 af2[2];
        #pragma unroll
        for (int c = 0; c < 2; ++c)
            af2[c] = (lr < 8) ? *(const f16x8*)(&sSH[lr][c * 32 + lg * 8]) : (f16x8)0;
        f32x4 a2[8];
        #pragma unroll
        for (int nt = 0; nt < 8; ++nt) a2[nt] = 0.0f;
        #pragma unroll
        for (int c = 0; c < 2; ++c)
            #pragma unroll
            for (int nt = 0; nt < 8; ++nt){
                const f16x8 b = *(const f16x8*)(ws2 + ((c * 8 + nt) * 64 + l) * 8);
                a2[nt] = __builtin_amdgcn_mfma_f32_16x16x32_f16(af2[c], b, a2[nt], 0, 0, 0);
            }
        if (lg < 2){
            #pragma unroll
            for (int nt = 0; nt < 8; ++nt)
                #pragma unroll
                for (int rr = 0; rr < 4; ++rr)
                    sSw[w][lg * 4 + rr][nt * 16 + lr] = a2[nt][rr] + b2v[nt];
        }
    }

    // ---- layer-2 edge MFMA (nfr/ga reused) ----
    f32x4 acc2[2][8];
    #pragma unroll
    for (int mt = 0; mt < 2; ++mt)
        #pragma unroll
        for (int nt = 0; nt < 8; ++nt) acc2[mt][nt] = 0.0f;
    #pragma unroll
    for (int c = 0; c < 2; ++c)
        #pragma unroll
        for (int nt = 0; nt < 8; ++nt){
            const f16x8 bn = *(const f16x8*)(wn2 + ((c * 8 + nt) * 64 + l) * 8);
            const f16x8 bg = *(const f16x8*)(wg2 + ((c * 8 + nt) * 64 + l) * 8);
            #pragma unroll
            for (int mt = 0; mt < 2; ++mt){
                acc2[mt][nt] = __builtin_amdgcn_mfma_f32_16x16x32_f16(nfr[mt][c], bn, acc2[mt][nt], 0, 0, 0);
                acc2[mt][nt] = __builtin_amdgcn_mfma_f32_16x16x32_f16(ga[mt][c],  bg, acc2[mt][nt], 0, 0, 0);
            }
        }

    // ---- z2 + LN2 -> prod ----
    #pragma unroll
    for (int mt = 0; mt < 2; ++mt){
        float s[4] = {0,0,0,0}, q[4] = {0,0,0,0};
        #pragma unroll
        for (int nt = 0; nt < 8; ++nt)
            #pragma unroll
            for (int rr = 0; rr < 4; ++rr){
                float v = acc2[mt][nt][rr] + sSw[w][aloc[mt][rr]][nt * 16 + lr];
                acc2[mt][nt][rr] = v;
                s[rr] += v; q[rr] += v * v;
            }
        #pragma unroll
        for (int rr = 0; rr < 4; ++rr){
            #pragma unroll
            for (int m = 1; m < 16; m <<= 1){
                s[rr] += __shfl_xor(s[rr], m);
                q[rr] += __shfl_xor(q[rr], m);
            }
        }
        #pragma unroll
        for (int rr = 0; rr < 4; ++rr){
            float mean = s[rr] * (1.0f / 128.0f);
            float var  = q[rr] * (1.0f / 128.0f) - mean * mean;
            float inv  = rsqrtf(var + LN_EPS);
            #pragma unroll
            for (int nt = 0; nt < 4; ++nt){
                float zf = (acc2[mt][nt][rr]     - mean) * inv * g2v[nt]     + be2v[nt];
                float zc = (acc2[mt][nt + 4][rr] - mean) * inv * g2v[nt + 4] + be2v[nt + 4];
                prod[w * 32 + mt * 16 + lg * 4 + rr][nt * 16 + lr] = sigmoidf_(zf) * softplusf_(zc);
            }
        }
    }
    __syncthreads();   // B3: prod2 complete

    // ---- epilogue 2 -> outF ----
    {
        int a_ = t >> 6, c = t & 63;
        float sm = 0.0f;
        #pragma unroll
        for (int m = 0; m < 12; ++m) sm += prod[a_ * 12 + m][c];
        outF[(long)blk * 512 + t] = softplusf_(sSF[a_][c] + sm);

        int i2 = t + 192; int a2_ = i2 >> 6, c2 = i2 & 63;
        float sm2 = 0.0f;
        #pragma unroll
        for (int m = 0; m < 12; ++m) sm2 += prod[a2_ * 12 + m][c2];
        outF[(long)blk * 512 + i2] = softplusf_(sSF[a2_][c2] + sm2);

        if (t < 128){
            int i3 = t + 384; int a3_ = i3 >> 6, c3 = i3 & 63;
            float sm3 = 0.0f;
            #pragma unroll
            for (int m = 0; m < 12; ++m) sm3 += prod[a3_ * 12 + m][c3];
            outF[(long)blk * 512 + i3] = softplusf_(sSF[a3_][c3] + sm3);
        }
    }
}

// ---------------- pooling: deterministic two-stage tree ----------------
__global__ __launch_bounds__(256) void k_partial(const float* __restrict__ atom,
        const float* __restrict__ occ, float* __restrict__ partials){
    int b = blockIdx.x, tid = threadIdx.x;
    int f = tid & 63, sub = tid >> 6;
    __shared__ float sAcc[256];
    float acc = 0.0f;
    for (int it = 0; it < 16; ++it){
        int a = b * 64 + sub + it * 4;
        float p = sigmoidf_(occ[a]);
        acc += atom[(long)a * FEA + f] * p;
    }
    sAcc[tid] = acc;
    __syncthreads();
    if (tid < 64){
        float s = sAcc[f] + sAcc[64 + f] + sAcc[128 + f] + sAcc[192 + f];
        partials[b * 65 + f] = s;
        float po = sigmoidf_(occ[b * 64 + f]);
        #pragma unroll
        for (int off = 32; off; off >>= 1) po += __shfl_down(po, off);
        if (f == 0) partials[b * 65 + 64] = po;
    }
}

__global__ __launch_bounds__(64) void k_final(const float* __restrict__ partials,
        const float* __restrict__ fc_w, const float* __restrict__ fc_b,
        float* __restrict__ out){
    int f = threadIdx.x;
    float num = 0.0f;
    for (int p = 0; p < 64; ++p) num += partials[p * 65 + f];
    float occs = partials[f * 65 + 64];
    #pragma unroll
    for (int off = 32; off; off >>= 1) occs += __shfl_down(occs, off);
    occs = __shfl(occs, 0);
    float gf = num / (occs + 1e-6f);
    float v = gf * fc_w[f];
    #pragma unroll
    for (int off = 32; off; off >>= 1) v += __shfl_down(v, off);
    if (f == 0) out[0] = v + fc_b[0];
}

extern "C" void kernel_launch(void* const* d_in, const int* in_sizes, int n_in,
                              void* d_out, int out_size, void* d_ws, size_t ws_size,
                              hipStream_t stream) {
    const float* lat    = (const float*)d_in[0];
    const float* fracs  = (const float*)d_in[1];
    const float* slog   = (const float*)d_in[2];
    const float* occ    = (const float*)d_in[3];
    const float* emb_w  = (const float*)d_in[4];
    const float* emb_b  = (const float*)d_in[5];
    const float* w1     = (const float*)d_in[6];
    const float* b1     = (const float*)d_in[7];
    const float* g1     = (const float*)d_in[8];
    const float* be1    = (const float*)d_in[9];
    const float* w2     = (const float*)d_in[10];
    const float* b2     = (const float*)d_in[11];
    const float* g2     = (const float*)d_in[12];
    const float* be2    = (const float*)d_in[13];
    const float* fc_w   = (const float*)d_in[14];
    const float* fc_b   = (const float*)d_in[15];
    float* out = (float*)d_out;

    char* ws = (char*)d_ws;
    auto alloc = [&](size_t bytes) -> void* {
        void* p = (void*)ws;
        ws += (bytes + 255) & ~(size_t)255;
        return p;
    };
    int*   nbr_idx  = (int*)  alloc((size_t)N_ATOMS * M_NBR * 4);
    float* nbr_dist = (float*)alloc((size_t)N_ATOMS * M_NBR * 4);
    float* atom0    = (float*)alloc((size_t)N_ATOMS * FEA * 4);
    float* atom1    = (float*)alloc((size_t)N_ATOMS * FEA * 4);
    u16*   a0f      = (u16*)  alloc((size_t)N_ATOMS * FEA * 2);
    u16*   wpk      = (u16*)  alloc((size_t)6 * 8192 * 2);
    float* fxa      = (float*)alloc((size_t)N_ATOMS * 4);
    float* fya      = (float*)alloc((size_t)N_ATOMS * 4);
    float* fza      = (float*)alloc((size_t)N_ATOMS * 4);
    float* partials = (float*)alloc((size_t)64 * 65 * 4);

    k_setup  <<<208 + N_ATOMS / 4, 256, 0, stream>>>(fracs, w1, w2, slog, emb_w, emb_b,
                fxa, fya, fza, wpk, atom0, a0f);
    k_topk   <<<N_ATOMS, 256, 0, stream>>>(fxa, fya, fza, lat, nbr_idx, nbr_dist);
    k_fused  <<<N_ATOMS / 8, 192, 0, stream>>>(atom0, a0f, nbr_idx, nbr_dist,
                wpk, b1, g1, be1, b2, g2, be2, atom1);
    k_partial<<<64, 256, 0, stream>>>(atom1, occ, partials);
    k_final  <<<1, 64, 0, stream>>>(partials, fc_w, fc_b, out);
}